// Round 4
// baseline (17977.516 us; speedup 1.0000x reference)
//
#include <hip/hip_runtime.h>
#include <hip/hip_bf16.h>
#include <hip/hip_cooperative_groups.h>

namespace cg = cooperative_groups;

#define BB 64
#define TT 128
#define FF 2048
#define HH 1024
#define CC 22
#define G4 4096      // 4*H
#define KD 2048      // decoder Z inner dim (attn | h)
#define BT 8192      // B*T

typedef __attribute__((ext_vector_type(8))) short bf16x8;
typedef __attribute__((ext_vector_type(4))) float f32x4;

__device__ __forceinline__ f32x4 mfma16(bf16x8 a, bf16x8 b, f32x4 c) {
    return __builtin_amdgcn_mfma_f32_16x16x32_bf16(a, b, c, 0, 0, 0);
}

__device__ __forceinline__ float b2f(short s) {
    unsigned int u = ((unsigned int)(unsigned short)s) << 16;
    union { unsigned int i; float f; } x; x.i = u; return x.f;
}

__device__ __forceinline__ short f2bs(float f) {
    union { __hip_bfloat16 h; short s; } u;
    u.h = __float2bfloat16(f);
    return u.s;
}

// gate-permutation: permuted row n' <- original row g*1024 + hb*4 + j where
// n' = hb*16 + g*4 + j.  src(n') = g*1024 + hb*4 + j.
__device__ __forceinline__ int gperm_src(int n) {
    return (((n >> 2) & 3) << 10) + ((n >> 4) << 2) + (n & 3);
}

// ---------------- utility kernels ----------------

__global__ void zero_u32(unsigned int* p, long long n) {
    long long i = (long long)blockIdx.x * 256 + threadIdx.x;
    if (i < n) p[i] = 0u;
}

__global__ void fill_f32(float* p, long long n, float v) {
    long long i = (long long)blockIdx.x * 256 + threadIdx.x;
    if (i < n) p[i] = v;
}

// dst[r*dld + c] = bf16(src[srcrow(r)*sld + soff + c]) for srcrow<valid else 0
__global__ void pack_bf16(const float* __restrict__ src, long long sld, long long soff,
                          __hip_bfloat16* __restrict__ dst, long long dld,
                          int rows, int cols, int valid, int perm) {
    long long i = (long long)blockIdx.x * 256 + threadIdx.x;
    long long tot = (long long)rows * cols;
    if (i >= tot) return;
    int r = (int)(i / cols), c = (int)(i % cols);
    int sr = perm ? gperm_src(r) : r;
    float v = (sr < valid) ? src[(long long)sr * sld + soff + c] : 0.f;
    dst[(long long)r * dld + c] = __float2bfloat16(v);
}

// dst[c*R + r] = bf16(src[r*C + c])   (transpose-convert)
__global__ void packT_bf16(const float* __restrict__ src, int R, int Ccols,
                           __hip_bfloat16* __restrict__ dst) {
    long long i = (long long)blockIdx.x * 256 + threadIdx.x;
    long long tot = (long long)R * Ccols;
    if (i >= tot) return;
    int r = (int)(i / Ccols), c = (int)(i % Ccols);
    dst[(long long)c * R + r] = __float2bfloat16(src[i]);
}

__global__ void add_bias2_perm(const float* a, const float* b, float* out, int n) {
    int i = blockIdx.x * 256 + threadIdx.x;
    if (i < n) { int s = gperm_src(i); out[i] = a[s] + b[s]; }
}

__global__ void pad_bias(const float* src, float* dst, int nsrc, int ndst) {
    int i = blockIdx.x * blockDim.x + threadIdx.x;
    if (i < ndst) dst[i] = (i < nsrc) ? src[i] : 0.f;
}

// badd[r] = dbih[s] + dbhh[s] + dot(dec_Wih[s, F:F+H], bd2e),  s = gperm_src(r)
__global__ __launch_bounds__(64) void bcomb_kernel(const float* __restrict__ dWih,
                                                   const float* __restrict__ bd2e,
                                                   const float* __restrict__ dbih,
                                                   const float* __restrict__ dbhh,
                                                   float* __restrict__ badd) {
    int r = blockIdx.x, lane = threadIdx.x;
    int s0 = gperm_src(r);
    const float* row = dWih + (long long)s0 * (FF + HH) + FF;
    float s = 0.f;
    for (int k = lane; k < HH; k += 64) s += row[k] * bd2e[k];
    #pragma unroll
    for (int off = 32; off; off >>= 1) s += __shfl_xor(s, off, 64);
    if (lane == 0) badd[r] = s + dbih[s0] + dbhh[s0];
}

// ---------------- MFMA GEMM: C[M,N] = A[M,K] @ W[N,K]^T (+bias) ----------------
// rowmap: 0 = identity; 1 = gate-perm the stored row (4096 rows);
//         2 = m(b*128+t) -> t*64+b (Xg [T,B,:] layout)
template <int K, bool AF32>
__global__ __launch_bounds__(256) void gemm_tile(
    const void* __restrict__ Aptr, long long lda,
    const __hip_bfloat16* __restrict__ W,
    const float* __restrict__ bias, void* __restrict__ Cout, int out_bf16,
    long long ldc, int n_store, int rowmap) {
    int tid = threadIdx.x;
    int wave = tid >> 6, lane = tid & 63;
    int wm = wave >> 1, wn = wave & 1;
    int m_base = blockIdx.x * 128 + wm * 64;
    int n_base = blockIdx.y * 128 + wn * 64;
    int row_in = lane & 15, k8 = (lane >> 4) * 8;

    f32x4 acc[4][4] = {};
    const float* Af = (const float*)Aptr + (long long)(m_base + row_in) * lda + k8;
    const __hip_bfloat16* Ab = (const __hip_bfloat16*)Aptr + (long long)(m_base + row_in) * lda + k8;
    const __hip_bfloat16* Wp = W + (long long)(n_base + row_in) * K + k8;

    #pragma unroll 2
    for (int k0 = 0; k0 < K; k0 += 32) {
        bf16x8 a[4], b[4];
        #pragma unroll
        for (int i = 0; i < 4; i++) {
            if (AF32) {
                const float* p = Af + (long long)i * 16 * lda + k0;
                #pragma unroll
                for (int j = 0; j < 8; j++) a[i][j] = f2bs(p[j]);
            } else {
                a[i] = *(const bf16x8*)(Ab + (long long)i * 16 * lda + k0);
            }
        }
        #pragma unroll
        for (int i = 0; i < 4; i++) b[i] = *(const bf16x8*)(Wp + (long long)i * 16 * K + k0);
        #pragma unroll
        for (int mt = 0; mt < 4; mt++)
            #pragma unroll
            for (int nt = 0; nt < 4; nt++)
                acc[mt][nt] = mfma16(a[mt], b[nt], acc[mt][nt]);
    }

    int col = lane & 15, rowq = (lane >> 4) * 4;
    #pragma unroll
    for (int mt = 0; mt < 4; mt++)
        #pragma unroll
        for (int nt = 0; nt < 4; nt++) {
            int n = n_base + nt * 16 + col;
            if (n >= n_store) continue;
            float bv = bias ? bias[n] : 0.f;
            #pragma unroll
            for (int r = 0; r < 4; r++) {
                long long m = m_base + mt * 16 + rowq + r;
                long long mr;
                if (rowmap == 1)      mr = ((m & 1023) >> 2) * 16 + (m >> 10) * 4 + (m & 3);
                else if (rowmap == 2) mr = (m & 127) * 64 + (m >> 7);
                else                  mr = m;
                float v = acc[mt][nt][r] + bv;
                if (out_bf16) ((__hip_bfloat16*)Cout)[mr * ldc + n] = __float2bfloat16(v);
                else          ((float*)Cout)[mr * ldc + n] = v;
            }
        }
}

// ---------------- persistent encoder: all 128 steps, 1 grid sync per step ----------------
// 256 blocks x 256 thr. Block b: permuted gate rows [16b,16b+16) = 4 gates x 4 h-cols
// (hc = 4b..4b+3). Wave w: K-slice [256w, 256w+256). W fragment preloaded in VGPRs.
// c-state: one register per thread (m = tid>>2, hc = 4b + (tid&3)).
__global__ __launch_bounds__(256) void enc_persist(
    const __hip_bfloat16* __restrict__ Wh,   // [4096][1024] gate-permuted
    const __hip_bfloat16* __restrict__ Xg,   // [128][64][4096] permuted cols
    __hip_bfloat16* __restrict__ h0buf,      // ping-pong [64][1024]
    __hip_bfloat16* __restrict__ h1buf,
    __hip_bfloat16* __restrict__ hts) {      // [64][128][1024]
    cg::grid_group grid = cg::this_grid();
    int bx = blockIdx.x, tid = threadIdx.x;
    int wave = tid >> 6, lane = tid & 63;
    int row_in = lane & 15, k8 = (lane >> 4) * 8;
    int col = lane & 15, rowq = (lane >> 4) * 4;
    __shared__ float gl[4][64][20];

    bf16x8 bw[8];
    const __hip_bfloat16* Wp = Wh + (long long)(bx * 16 + row_in) * HH + wave * 256 + k8;
    #pragma unroll
    for (int i = 0; i < 8; i++) bw[i] = *(const bf16x8*)(Wp + 32 * i);

    int m_own = tid >> 2, j_own = tid & 3;
    int hc = bx * 4 + j_own;
    float creg = 0.f;

    for (int t = 0; t < TT; t++) {
        const __hip_bfloat16* Z = (t & 1) ? h1buf : h0buf;
        const __hip_bfloat16* Zp = Z + row_in * HH + wave * 256 + k8;
        f32x4 acc[4] = {};
        #pragma unroll
        for (int i = 0; i < 8; i++) {
            #pragma unroll
            for (int mt = 0; mt < 4; mt++) {
                bf16x8 a = *(const bf16x8*)(Zp + mt * 16 * HH + 32 * i);
                acc[mt] = mfma16(a, bw[i], acc[mt]);
            }
        }
        #pragma unroll
        for (int mt = 0; mt < 4; mt++)
            #pragma unroll
            for (int r = 0; r < 4; r++)
                gl[wave][mt * 16 + rowq + r][col] = acc[mt][r];
        __syncthreads();

        float gv[4];
        #pragma unroll
        for (int g = 0; g < 4; g++)
            gv[g] = gl[0][m_own][g * 4 + j_own] + gl[1][m_own][g * 4 + j_own]
                  + gl[2][m_own][g * 4 + j_own] + gl[3][m_own][g * 4 + j_own]
                  + __bfloat162float(Xg[((long long)t * 64 + m_own) * G4 + bx * 16 + g * 4 + j_own]);
        float si = 1.f / (1.f + __expf(-gv[0]));
        float sf = 1.f / (1.f + __expf(-gv[1]));
        float tg = tanhf(gv[2]);
        float so = 1.f / (1.f + __expf(-gv[3]));
        creg = sf * creg + si * tg;
        float hn = so * tanhf(creg);
        __hip_bfloat16 hb = __float2bfloat16(hn);
        ((t & 1) ? h0buf : h1buf)[m_own * HH + hc] = hb;
        hts[((long long)m_own * TT + t) * HH + hc] = hb;
        grid.sync();
    }
}

// ---------------- persistent decoder: attention + gates + update, 2 syncs/step ----------------
__global__ __launch_bounds__(256) void dec_persist(
    const __hip_bfloat16* __restrict__ Wz,   // [4096][2048] gate-permuted
    const __hip_bfloat16* __restrict__ Xg,   // [128][64][4096] permuted cols
    const __hip_bfloat16* __restrict__ proj, // [64][128][1024]
    __hip_bfloat16* __restrict__ Z0,         // ping-pong [64][2048]
    __hip_bfloat16* __restrict__ Z1,
    float* __restrict__ hdec,                // [64][1024] fp32
    __hip_bfloat16* __restrict__ hdts,       // [64][128][1024]
    float* __restrict__ aw_out) {            // [64][128]
    cg::grid_group grid = cg::this_grid();
    int bx = blockIdx.x, tid = threadIdx.x;
    int wave = tid >> 6, lane = tid & 63;
    int row_in = lane & 15, k8 = (lane >> 4) * 8;
    int col = lane & 15, rowq = (lane >> 4) * 4;
    __shared__ float gl[4][64][20];
    __shared__ float osum[4][HH];
    __shared__ float logits[TT];
    __shared__ float wm_s[4], wl_s[4];

    bf16x8 bw[16];
    const __hip_bfloat16* Wp = Wz + (long long)(bx * 16 + row_in) * KD + wave * 512 + k8;
    #pragma unroll
    for (int i = 0; i < 16; i++) bw[i] = *(const bf16x8*)(Wp + 32 * i);

    int m_own = tid >> 2, j_own = tid & 3;
    int hc = bx * 4 + j_own;
    float creg = 0.f;
    const float scale = 0.03125f;  // 1/sqrt(1024)

    for (int t = 0; t < TT; t++) {
        __hip_bfloat16* Zcur = (t & 1) ? Z1 : Z0;
        __hip_bfloat16* Znxt = (t & 1) ? Z0 : Z1;

        // ---- attention phase: blocks 0..63, batch = bx ----
        if (bx < BB) {
            float hreg[16];
            const float* hp = hdec + (long long)bx * HH + lane * 16;
            #pragma unroll
            for (int j = 0; j < 16; j++) hreg[j] = hp[j];
            float mx = -1e30f, l = 0.f;
            float o[16];
            #pragma unroll
            for (int j = 0; j < 16; j++) o[j] = 0.f;
            const __hip_bfloat16* pb = proj + (long long)bx * TT * HH + lane * 16;
            for (int tt = wave; tt < TT; tt += 4) {
                const __hip_bfloat16* p = pb + (long long)tt * HH;
                bf16x8 p0 = *(const bf16x8*)(p);
                bf16x8 p1 = *(const bf16x8*)(p + 8);
                float pv[16];
                #pragma unroll
                for (int j = 0; j < 8; j++) { pv[j] = b2f(p0[j]); pv[8 + j] = b2f(p1[j]); }
                float dot = 0.f;
                #pragma unroll
                for (int j = 0; j < 16; j++) dot += hreg[j] * pv[j];
                #pragma unroll
                for (int off = 32; off; off >>= 1) dot += __shfl_xor(dot, off, 64);
                dot *= scale;
                if (lane == 0) logits[tt] = dot;
                float mn = fmaxf(mx, dot);
                float alpha = __expf(mx - mn);
                float w = __expf(dot - mn);
                l = l * alpha + w;
                #pragma unroll
                for (int j = 0; j < 16; j++) o[j] = o[j] * alpha + w * pv[j];
                mx = mn;
            }
            if (lane == 0) { wm_s[wave] = mx; wl_s[wave] = l; }
            #pragma unroll
            for (int j = 0; j < 16; j++) osum[wave][lane * 16 + j] = o[j];
            __syncthreads();
            float m0 = wm_s[0], m1 = wm_s[1], m2 = wm_s[2], m3 = wm_s[3];
            float mstar = fmaxf(fmaxf(m0, m1), fmaxf(m2, m3));
            float f0 = __expf(m0 - mstar), f1 = __expf(m1 - mstar);
            float f2 = __expf(m2 - mstar), f3 = __expf(m3 - mstar);
            float L = f0 * wl_s[0] + f1 * wl_s[1] + f2 * wl_s[2] + f3 * wl_s[3];
            float invL = 1.f / L;
            #pragma unroll
            for (int j = 0; j < 4; j++) {
                int k = tid * 4 + j;
                float s = f0 * osum[0][k] + f1 * osum[1][k] + f2 * osum[2][k] + f3 * osum[3][k];
                Zcur[(long long)bx * KD + k] = __float2bfloat16(s * invL);
            }
            if (t == TT - 1 && tid < TT)
                aw_out[(long long)bx * TT + tid] = __expf(logits[tid] - mstar) * invL;
        }
        grid.sync();

        // ---- gates GEMM phase ----
        const __hip_bfloat16* Zp = Zcur + row_in * KD + wave * 512 + k8;
        f32x4 acc[4] = {};
        #pragma unroll 4
        for (int i = 0; i < 16; i++) {
            #pragma unroll
            for (int mt = 0; mt < 4; mt++) {
                bf16x8 a = *(const bf16x8*)(Zp + mt * 16 * KD + 32 * i);
                acc[mt] = mfma16(a, bw[i], acc[mt]);
            }
        }
        #pragma unroll
        for (int mt = 0; mt < 4; mt++)
            #pragma unroll
            for (int r = 0; r < 4; r++)
                gl[wave][mt * 16 + rowq + r][col] = acc[mt][r];
        __syncthreads();

        float gv[4];
        #pragma unroll
        for (int g = 0; g < 4; g++)
            gv[g] = gl[0][m_own][g * 4 + j_own] + gl[1][m_own][g * 4 + j_own]
                  + gl[2][m_own][g * 4 + j_own] + gl[3][m_own][g * 4 + j_own]
                  + __bfloat162float(Xg[((long long)t * 64 + m_own) * G4 + bx * 16 + g * 4 + j_own]);
        float si = 1.f / (1.f + __expf(-gv[0]));
        float sf = 1.f / (1.f + __expf(-gv[1]));
        float tg = tanhf(gv[2]);
        float so = 1.f / (1.f + __expf(-gv[3]));
        creg = sf * creg + si * tg;
        float hn = so * tanhf(creg);
        __hip_bfloat16 hb = __float2bfloat16(hn);
        Znxt[(long long)m_own * KD + HH + hc] = hb;
        hdec[(long long)m_own * HH + hc] = hn;
        hdts[((long long)m_own * TT + t) * HH + hc] = hb;
        grid.sync();
    }
}

// ---------------- host ----------------

extern "C" void kernel_launch(void* const* d_in, const int* in_sizes, int n_in,
                              void* d_out, int out_size, void* d_ws, size_t ws_size,
                              hipStream_t stream) {
    const float* x    = (const float*)d_in[0];
    const float* eWih = (const float*)d_in[1];
    const float* eWhh = (const float*)d_in[2];
    const float* ebih = (const float*)d_in[3];
    const float* ebhh = (const float*)d_in[4];
    const float* We2d = (const float*)d_in[5];
    const float* be2d = (const float*)d_in[6];
    const float* Wd2e = (const float*)d_in[7];
    const float* bd2e = (const float*)d_in[8];
    const float* dWih = (const float*)d_in[9];
    const float* dWhh = (const float*)d_in[10];
    const float* dbih = (const float*)d_in[11];
    const float* dbhh = (const float*)d_in[12];
    const float* Wc   = (const float*)d_in[13];
    const float* bc   = (const float*)d_in[14];

    float* scores = (float*)d_out;                  // [B,T,C]
    float* aw_out = scores + (size_t)BB * TT * CC;  // [B,T]

    char* ws = (char*)d_ws;
    size_t off = 0;
    auto alloc = [&](size_t bytes) -> char* {
        char* p = ws + off;
        off = (off + bytes + 255) & ~(size_t)255;
        return p;
    };

    __hip_bfloat16* Xg    = (__hip_bfloat16*)alloc((size_t)BT * G4 * 2);   // 64 MiB, [T,B,4H], enc then dec
    char*           Bz    = alloc((size_t)G4 * KD * 2);                    // 16 MiB: eWhhB (enc) then Wz (dec)
    char*           Cp    = alloc((size_t)G4 * FF * 2);                    // 16 MiB: eWihB -> dWxB -> proj
    __hip_bfloat16* hts   = (__hip_bfloat16*)alloc((size_t)BT * HH * 2);   // 16 MiB: hts then hdts
    __hip_bfloat16* Wd2eT = (__hip_bfloat16*)alloc((size_t)HH * HH * 2);   // 2 MiB
    __hip_bfloat16* We2dB = (__hip_bfloat16*)alloc((size_t)HH * HH * 2);   // 2 MiB
    __hip_bfloat16* WcP   = (__hip_bfloat16*)alloc((size_t)128 * HH * 2);  // 256 KiB
    float*          encb  = (float*)alloc((size_t)G4 * 4);
    float*          badd  = (float*)alloc((size_t)G4 * 4);
    float*          bcP   = (float*)alloc((size_t)128 * 4);
    // state (zeroed each call): henc0|henc1|Z0|Z1|hdec = 1 MiB
    char*           state = alloc(1048576);
    __hip_bfloat16* henc0 = (__hip_bfloat16*)(state);
    __hip_bfloat16* henc1 = (__hip_bfloat16*)(state + 131072);
    __hip_bfloat16* Zb0   = (__hip_bfloat16*)(state + 262144);
    __hip_bfloat16* Zb1   = (__hip_bfloat16*)(state + 524288);
    float*          hdec  = (float*)(state + 786432);

    __hip_bfloat16* eWhhB = (__hip_bfloat16*)Bz;     // encoder phase
    __hip_bfloat16* Wz    = (__hip_bfloat16*)Bz;     // decoder phase (overwrites)
    __hip_bfloat16* eWihB = (__hip_bfloat16*)Cp;     // phase 1
    __hip_bfloat16* dWxB  = (__hip_bfloat16*)Cp;     // phase 2
    __hip_bfloat16* proj  = (__hip_bfloat16*)Cp;     // phase 3
    __hip_bfloat16* hdts  = hts;                     // decoder phase

    (void)in_sizes; (void)n_in;

    if (off > ws_size) {
        long long n = out_size;
        fill_f32<<<dim3((unsigned)((n + 255) / 256)), 256, 0, stream>>>((float*)d_out, n, 111.0f);
        return;
    }

    auto packGrid = [](long long tot) { return dim3((unsigned)((tot + 255) / 256)); };

    // ---- setup (weights gate-permuted where indexed by the 4096 dim) ----
    zero_u32<<<dim3(1024), dim3(256), 0, stream>>>((unsigned int*)state, 262144LL);
    pack_bf16<<<packGrid((long long)G4 * FF), 256, 0, stream>>>(eWih, FF, 0, eWihB, FF, G4, FF, G4, 1);
    pack_bf16<<<packGrid((long long)G4 * HH), 256, 0, stream>>>(eWhh, HH, 0, eWhhB, HH, G4, HH, G4, 1);
    packT_bf16<<<packGrid((long long)HH * HH), 256, 0, stream>>>(Wd2e, HH, HH, Wd2eT);
    pack_bf16<<<packGrid((long long)HH * HH), 256, 0, stream>>>(We2d, HH, 0, We2dB, HH, HH, HH, HH, 0);
    pack_bf16<<<packGrid((long long)128 * HH), 256, 0, stream>>>(Wc, HH, 0, WcP, HH, 128, HH, CC, 0);
    add_bias2_perm<<<16, 256, 0, stream>>>(ebih, ebhh, encb, G4);
    pad_bias<<<1, 128, 0, stream>>>(bc, bcP, CC, 128);
    bcomb_kernel<<<G4, 64, 0, stream>>>(dWih, bd2e, dbih, dbhh, badd);

    // enc Xg = bf16(x @ enc_Wih^T + bias)  -> [T,B,4096] (rowmap=2)
    gemm_tile<FF, true><<<dim3(BT / 128, G4 / 128), 256, 0, stream>>>(
        x, FF, eWihB, encb, Xg, 1, G4, G4, 2);

    // ---- persistent encoder (cooperative) ----
    {
        const __hip_bfloat16* a0 = eWhhB; const __hip_bfloat16* a1 = Xg;
        __hip_bfloat16* a2 = henc0; __hip_bfloat16* a3 = henc1; __hip_bfloat16* a4 = hts;
        void* args[5] = { &a0, &a1, &a2, &a3, &a4 };
        hipLaunchCooperativeKernel((const void*)enc_persist, dim3(256), dim3(256), args, 0, stream);
    }

    // dec Xg = bf16(x @ dec_Wih[:, :F]^T + badd)  (Cp: eWihB -> dWxB)
    pack_bf16<<<packGrid((long long)G4 * FF), 256, 0, stream>>>(dWih, FF + HH, 0, dWxB, FF, G4, FF, G4, 1);
    gemm_tile<FF, true><<<dim3(BT / 128, G4 / 128), 256, 0, stream>>>(
        x, FF, dWxB, badd, Xg, 1, G4, G4, 2);

    // Wz[:, 0:1024] = perm_rows(dec_Wih[:, F:] @ Wd2e)   (rowmap=1)
    gemm_tile<HH, true><<<dim3(G4 / 128, HH / 128), 256, 0, stream>>>(
        dWih + FF, FF + HH, Wd2eT, nullptr, Wz, 1, KD, HH, 1);
    // Wz[:, 1024:2048] = perm_rows(dec_Whh)
    pack_bf16<<<packGrid((long long)G4 * HH), 256, 0, stream>>>(dWhh, HH, 0, Wz + HH, KD, G4, HH, G4, 1);

    // proj = h_ts @ We2d^T + be2d  (bf16 out; Cp: dWxB -> proj)
    gemm_tile<HH, false><<<dim3(BT / 128, HH / 128), 256, 0, stream>>>(
        hts, HH, We2dB, be2d, proj, 1, HH, HH, 0);

    // ---- persistent decoder (cooperative) ----
    {
        const __hip_bfloat16* a0 = Wz; const __hip_bfloat16* a1 = Xg;
        const __hip_bfloat16* a2 = proj;
        __hip_bfloat16* a3 = Zb0; __hip_bfloat16* a4 = Zb1;
        float* a5 = hdec; __hip_bfloat16* a6 = hdts; float* a7 = aw_out;
        void* args[8] = { &a0, &a1, &a2, &a3, &a4, &a5, &a6, &a7 };
        hipLaunchCooperativeKernel((const void*)dec_persist, dim3(256), dim3(256), args, 0, stream);
    }

    // scores = h_dec_ts @ Wc^T + bc   (N padded to 128, store n<22, ldc=22)
    gemm_tile<HH, false><<<dim3(BT / 128, 1), 256, 0, stream>>>(
        hdts, HH, WcP, bcP, scores, 0, CC, CC, 0);
}

// Round 6
// 17566.495 us; speedup vs baseline: 1.0234x; 1.0234x over previous
//
#include <hip/hip_runtime.h>
#include <hip/hip_bf16.h>
#include <hip/hip_cooperative_groups.h>

namespace cg = cooperative_groups;

#define BB 64
#define TT 128
#define FF 2048
#define HH 1024
#define CC 22
#define G4 4096      // 4*H
#define KD 2048      // decoder Z inner dim (attn | h)
#define BT 8192      // B*T

typedef __attribute__((ext_vector_type(8))) short bf16x8;
typedef __attribute__((ext_vector_type(4))) float f32x4;

__device__ __forceinline__ f32x4 mfma16(bf16x8 a, bf16x8 b, f32x4 c) {
    return __builtin_amdgcn_mfma_f32_16x16x32_bf16(a, b, c, 0, 0, 0);
}

__device__ __forceinline__ float b2f(short s) {
    unsigned int u = ((unsigned int)(unsigned short)s) << 16;
    union { unsigned int i; float f; } x; x.i = u; return x.f;
}

__device__ __forceinline__ short f2bs(float f) {
    union { __hip_bfloat16 h; short s; } u;
    u.h = __float2bfloat16(f);
    return u.s;
}

// gate-permutation: permuted row n' <- original row g*1024 + hb*4 + j where
// n' = hb*16 + g*4 + j.  src(n') = g*1024 + hb*4 + j.
__device__ __forceinline__ int gperm_src(int n) {
    return (((n >> 2) & 3) << 10) + ((n >> 4) << 2) + (n & 3);
}

// ---------------- utility kernels ----------------

__global__ void zero_u32(unsigned int* p, long long n) {
    long long i = (long long)blockIdx.x * 256 + threadIdx.x;
    if (i < n) p[i] = 0u;
}

__global__ void fill_f32(float* p, long long n, float v) {
    long long i = (long long)blockIdx.x * 256 + threadIdx.x;
    if (i < n) p[i] = v;
}

__global__ void pack_bf16(const float* __restrict__ src, long long sld, long long soff,
                          __hip_bfloat16* __restrict__ dst, long long dld,
                          int rows, int cols, int valid, int perm) {
    long long i = (long long)blockIdx.x * 256 + threadIdx.x;
    long long tot = (long long)rows * cols;
    if (i >= tot) return;
    int r = (int)(i / cols), c = (int)(i % cols);
    int sr = perm ? gperm_src(r) : r;
    float v = (sr < valid) ? src[(long long)sr * sld + soff + c] : 0.f;
    dst[(long long)r * dld + c] = __float2bfloat16(v);
}

__global__ void packT_bf16(const float* __restrict__ src, int R, int Ccols,
                           __hip_bfloat16* __restrict__ dst) {
    long long i = (long long)blockIdx.x * 256 + threadIdx.x;
    long long tot = (long long)R * Ccols;
    if (i >= tot) return;
    int r = (int)(i / Ccols), c = (int)(i % Ccols);
    dst[(long long)c * R + r] = __float2bfloat16(src[i]);
}

__global__ void add_bias2_perm(const float* a, const float* b, float* out, int n) {
    int i = blockIdx.x * 256 + threadIdx.x;
    if (i < n) { int s = gperm_src(i); out[i] = a[s] + b[s]; }
}

__global__ void pad_bias(const float* src, float* dst, int nsrc, int ndst) {
    int i = blockIdx.x * blockDim.x + threadIdx.x;
    if (i < ndst) dst[i] = (i < nsrc) ? src[i] : 0.f;
}

__global__ __launch_bounds__(64) void bcomb_kernel(const float* __restrict__ dWih,
                                                   const float* __restrict__ bd2e,
                                                   const float* __restrict__ dbih,
                                                   const float* __restrict__ dbhh,
                                                   float* __restrict__ badd) {
    int r = blockIdx.x, lane = threadIdx.x;
    int s0 = gperm_src(r);
    const float* row = dWih + (long long)s0 * (FF + HH) + FF;
    float s = 0.f;
    for (int k = lane; k < HH; k += 64) s += row[k] * bd2e[k];
    #pragma unroll
    for (int off = 32; off; off >>= 1) s += __shfl_xor(s, off, 64);
    if (lane == 0) badd[r] = s + dbih[s0] + dbhh[s0];
}

// ---------------- MFMA GEMM: C[M,N] = A[M,K] @ W[N,K]^T (+bias) ----------------
// rowmap: 0 = identity; 1 = gate-perm the stored row (4096 rows);
//         2 = m(b*128+t) -> t*64+b (Xg [T,B,:] layout)
template <int K, bool AF32>
__global__ __launch_bounds__(256) void gemm_tile(
    const void* __restrict__ Aptr, long long lda,
    const __hip_bfloat16* __restrict__ W,
    const float* __restrict__ bias, void* __restrict__ Cout, int out_bf16,
    long long ldc, int n_store, int rowmap) {
    int tid = threadIdx.x;
    int wave = tid >> 6, lane = tid & 63;
    int wm = wave >> 1, wn = wave & 1;
    int m_base = blockIdx.x * 128 + wm * 64;
    int n_base = blockIdx.y * 128 + wn * 64;
    int row_in = lane & 15, k8 = (lane >> 4) * 8;

    f32x4 acc[4][4] = {};
    const float* Af = (const float*)Aptr + (long long)(m_base + row_in) * lda + k8;
    const __hip_bfloat16* Ab = (const __hip_bfloat16*)Aptr + (long long)(m_base + row_in) * lda + k8;
    const __hip_bfloat16* Wp = W + (long long)(n_base + row_in) * K + k8;

    #pragma unroll 2
    for (int k0 = 0; k0 < K; k0 += 32) {
        bf16x8 a[4], b[4];
        #pragma unroll
        for (int i = 0; i < 4; i++) {
            if (AF32) {
                const float4* p4 = (const float4*)(Af + (long long)i * 16 * lda + k0);
                float4 v0 = p4[0], v1 = p4[1];
                a[i][0] = f2bs(v0.x); a[i][1] = f2bs(v0.y);
                a[i][2] = f2bs(v0.z); a[i][3] = f2bs(v0.w);
                a[i][4] = f2bs(v1.x); a[i][5] = f2bs(v1.y);
                a[i][6] = f2bs(v1.z); a[i][7] = f2bs(v1.w);
            } else {
                a[i] = *(const bf16x8*)(Ab + (long long)i * 16 * lda + k0);
            }
        }
        #pragma unroll
        for (int i = 0; i < 4; i++) b[i] = *(const bf16x8*)(Wp + (long long)i * 16 * K + k0);
        #pragma unroll
        for (int mt = 0; mt < 4; mt++)
            #pragma unroll
            for (int nt = 0; nt < 4; nt++)
                acc[mt][nt] = mfma16(a[mt], b[nt], acc[mt][nt]);
    }

    int col = lane & 15, rowq = (lane >> 4) * 4;
    #pragma unroll
    for (int mt = 0; mt < 4; mt++)
        #pragma unroll
        for (int nt = 0; nt < 4; nt++) {
            int n = n_base + nt * 16 + col;
            if (n >= n_store) continue;
            float bv = bias ? bias[n] : 0.f;
            #pragma unroll
            for (int r = 0; r < 4; r++) {
                long long m = m_base + mt * 16 + rowq + r;
                long long mr;
                if (rowmap == 1)      mr = ((m & 1023) >> 2) * 16 + (m >> 10) * 4 + (m & 3);
                else if (rowmap == 2) mr = (m & 127) * 64 + (m >> 7);
                else                  mr = m;
                float v = acc[mt][nt][r] + bv;
                if (out_bf16) ((__hip_bfloat16*)Cout)[mr * ldc + n] = __float2bfloat16(v);
                else          ((float*)Cout)[mr * ldc + n] = v;
            }
        }
}

// ---------------- persistent encoder (round-4 proven) ----------------
__global__ __launch_bounds__(256) void enc_persist(
    const __hip_bfloat16* __restrict__ Wh,   // [4096][1024] gate-permuted
    const __hip_bfloat16* __restrict__ Xg,   // [128][64][4096] permuted cols
    __hip_bfloat16* __restrict__ h0buf,      // ping-pong [64][1024]
    __hip_bfloat16* __restrict__ h1buf,
    __hip_bfloat16* __restrict__ hts) {      // [64][128][1024]
    cg::grid_group grid = cg::this_grid();
    int bx = blockIdx.x, tid = threadIdx.x;
    int wave = tid >> 6, lane = tid & 63;
    int row_in = lane & 15, k8 = (lane >> 4) * 8;
    int col = lane & 15, rowq = (lane >> 4) * 4;
    __shared__ float gl[4][64][20];

    bf16x8 bw[8];
    const __hip_bfloat16* Wp = Wh + (long long)(bx * 16 + row_in) * HH + wave * 256 + k8;
    #pragma unroll
    for (int i = 0; i < 8; i++) bw[i] = *(const bf16x8*)(Wp + 32 * i);

    int m_own = tid >> 2, j_own = tid & 3;
    int hc = bx * 4 + j_own;
    float creg = 0.f;

    for (int t = 0; t < TT; t++) {
        const __hip_bfloat16* Z = (t & 1) ? h1buf : h0buf;
        const __hip_bfloat16* Zp = Z + row_in * HH + wave * 256 + k8;
        f32x4 acc[4] = {};
        #pragma unroll
        for (int i = 0; i < 8; i++) {
            #pragma unroll
            for (int mt = 0; mt < 4; mt++) {
                bf16x8 a = *(const bf16x8*)(Zp + mt * 16 * HH + 32 * i);
                acc[mt] = mfma16(a, bw[i], acc[mt]);
            }
        }
        #pragma unroll
        for (int mt = 0; mt < 4; mt++)
            #pragma unroll
            for (int r = 0; r < 4; r++)
                gl[wave][mt * 16 + rowq + r][col] = acc[mt][r];
        __syncthreads();

        float gv[4];
        #pragma unroll
        for (int g = 0; g < 4; g++)
            gv[g] = gl[0][m_own][g * 4 + j_own] + gl[1][m_own][g * 4 + j_own]
                  + gl[2][m_own][g * 4 + j_own] + gl[3][m_own][g * 4 + j_own]
                  + __bfloat162float(Xg[((long long)t * 64 + m_own) * G4 + bx * 16 + g * 4 + j_own]);
        float si = 1.f / (1.f + __expf(-gv[0]));
        float sf = 1.f / (1.f + __expf(-gv[1]));
        float tg = tanhf(gv[2]);
        float so = 1.f / (1.f + __expf(-gv[3]));
        creg = sf * creg + si * tg;
        float hn = so * tanhf(creg);
        __hip_bfloat16 hb = __float2bfloat16(hn);
        ((t & 1) ? h0buf : h1buf)[m_own * HH + hc] = hb;
        hts[((long long)m_own * TT + t) * HH + hc] = hb;
        grid.sync();
    }
}

// ---------------- persistent decoder (round-4 proven structure) ----------------
// Attention phase: blocks with (bx&3)==0, batch b = bx>>2 — strided so the 64
// attention blocks spread across XCDs; each XCD then holds ~8 batches x 256KB
// of proj = 2MB, L2-resident (round-4's contiguous 0..63 put 8MB on one XCD).
__global__ __launch_bounds__(256) void dec_persist(
    const __hip_bfloat16* __restrict__ Wz,   // [4096][2048] gate-permuted
    const __hip_bfloat16* __restrict__ Xg,   // [128][64][4096] permuted cols
    const __hip_bfloat16* __restrict__ proj, // [64][128][1024]
    __hip_bfloat16* __restrict__ Z0,         // ping-pong [64][2048]
    __hip_bfloat16* __restrict__ Z1,
    float* __restrict__ hdec,                // [64][1024] fp32
    __hip_bfloat16* __restrict__ hdts,       // [64][128][1024]
    float* __restrict__ aw_out) {            // [64][128]
    cg::grid_group grid = cg::this_grid();
    int bx = blockIdx.x, tid = threadIdx.x;
    int wave = tid >> 6, lane = tid & 63;
    int row_in = lane & 15, k8 = (lane >> 4) * 8;
    int col = lane & 15, rowq = (lane >> 4) * 4;
    __shared__ float gl[4][64][20];
    __shared__ float osum[4][HH];
    __shared__ float logits[TT];
    __shared__ float wm_s[4], wl_s[4];

    bf16x8 bw[16];
    const __hip_bfloat16* Wp = Wz + (long long)(bx * 16 + row_in) * KD + wave * 512 + k8;
    #pragma unroll
    for (int i = 0; i < 16; i++) bw[i] = *(const bf16x8*)(Wp + 32 * i);

    int m_own = tid >> 2, j_own = tid & 3;
    int hc = bx * 4 + j_own;
    float creg = 0.f;
    const float scale = 0.03125f;  // 1/sqrt(1024)

    for (int t = 0; t < TT; t++) {
        __hip_bfloat16* Zcur = (t & 1) ? Z1 : Z0;
        __hip_bfloat16* Znxt = (t & 1) ? Z0 : Z1;

        // ---- attention phase: strided blocks, batch = bx>>2 ----
        if ((bx & 3) == 0) {
            const int b = bx >> 2;
            float hreg[16];
            const float* hp = hdec + (long long)b * HH + lane * 16;
            #pragma unroll
            for (int j = 0; j < 16; j++) hreg[j] = hp[j];
            float mx = -1e30f, l = 0.f;
            float o[16];
            #pragma unroll
            for (int j = 0; j < 16; j++) o[j] = 0.f;
            const __hip_bfloat16* pb = proj + (long long)b * TT * HH + lane * 16;
            for (int tt = wave; tt < TT; tt += 4) {
                const __hip_bfloat16* p = pb + (long long)tt * HH;
                bf16x8 p0 = *(const bf16x8*)(p);
                bf16x8 p1 = *(const bf16x8*)(p + 8);
                float pv[16];
                #pragma unroll
                for (int j = 0; j < 8; j++) { pv[j] = b2f(p0[j]); pv[8 + j] = b2f(p1[j]); }
                float dot = 0.f;
                #pragma unroll
                for (int j = 0; j < 16; j++) dot += hreg[j] * pv[j];
                #pragma unroll
                for (int off = 32; off; off >>= 1) dot += __shfl_xor(dot, off, 64);
                dot *= scale;
                if (lane == 0) logits[tt] = dot;
                float mn = fmaxf(mx, dot);
                float alpha = __expf(mx - mn);
                float w = __expf(dot - mn);
                l = l * alpha + w;
                #pragma unroll
                for (int j = 0; j < 16; j++) o[j] = o[j] * alpha + w * pv[j];
                mx = mn;
            }
            if (lane == 0) { wm_s[wave] = mx; wl_s[wave] = l; }
            #pragma unroll
            for (int j = 0; j < 16; j++) osum[wave][lane * 16 + j] = o[j];
            __syncthreads();
            float m0 = wm_s[0], m1 = wm_s[1], m2 = wm_s[2], m3 = wm_s[3];
            float mstar = fmaxf(fmaxf(m0, m1), fmaxf(m2, m3));
            float f0 = __expf(m0 - mstar), f1 = __expf(m1 - mstar);
            float f2 = __expf(m2 - mstar), f3 = __expf(m3 - mstar);
            float L = f0 * wl_s[0] + f1 * wl_s[1] + f2 * wl_s[2] + f3 * wl_s[3];
            float invL = 1.f / L;
            #pragma unroll
            for (int j = 0; j < 4; j++) {
                int k = tid * 4 + j;
                float s = f0 * osum[0][k] + f1 * osum[1][k] + f2 * osum[2][k] + f3 * osum[3][k];
                Zcur[(long long)b * KD + k] = __float2bfloat16(s * invL);
            }
            if (t == TT - 1 && tid < TT)
                aw_out[(long long)b * TT + tid] = __expf(logits[tid] - mstar) * invL;
        }
        grid.sync();

        // ---- gates GEMM phase ----
        const __hip_bfloat16* Zp = Zcur + row_in * KD + wave * 512 + k8;
        f32x4 acc[4] = {};
        #pragma unroll 4
        for (int i = 0; i < 16; i++) {
            #pragma unroll
            for (int mt = 0; mt < 4; mt++) {
                bf16x8 a = *(const bf16x8*)(Zp + mt * 16 * KD + 32 * i);
                acc[mt] = mfma16(a, bw[i], acc[mt]);
            }
        }
        #pragma unroll
        for (int mt = 0; mt < 4; mt++)
            #pragma unroll
            for (int r = 0; r < 4; r++)
                gl[wave][mt * 16 + rowq + r][col] = acc[mt][r];
        __syncthreads();

        float gv[4];
        #pragma unroll
        for (int g = 0; g < 4; g++)
            gv[g] = gl[0][m_own][g * 4 + j_own] + gl[1][m_own][g * 4 + j_own]
                  + gl[2][m_own][g * 4 + j_own] + gl[3][m_own][g * 4 + j_own]
                  + __bfloat162float(Xg[((long long)t * 64 + m_own) * G4 + bx * 16 + g * 4 + j_own]);
        float si = 1.f / (1.f + __expf(-gv[0]));
        float sf = 1.f / (1.f + __expf(-gv[1]));
        float tg = tanhf(gv[2]);
        float so = 1.f / (1.f + __expf(-gv[3]));
        creg = sf * creg + si * tg;
        float hn = so * tanhf(creg);
        __hip_bfloat16 hb = __float2bfloat16(hn);
        Znxt[(long long)m_own * KD + HH + hc] = hb;
        hdec[(long long)m_own * HH + hc] = hn;
        hdts[((long long)m_own * TT + t) * HH + hc] = hb;
        grid.sync();
    }
}

// ---------------- host ----------------

extern "C" void kernel_launch(void* const* d_in, const int* in_sizes, int n_in,
                              void* d_out, int out_size, void* d_ws, size_t ws_size,
                              hipStream_t stream) {
    const float* x    = (const float*)d_in[0];
    const float* eWih = (const float*)d_in[1];
    const float* eWhh = (const float*)d_in[2];
    const float* ebih = (const float*)d_in[3];
    const float* ebhh = (const float*)d_in[4];
    const float* We2d = (const float*)d_in[5];
    const float* be2d = (const float*)d_in[6];
    const float* Wd2e = (const float*)d_in[7];
    const float* bd2e = (const float*)d_in[8];
    const float* dWih = (const float*)d_in[9];
    const float* dWhh = (const float*)d_in[10];
    const float* dbih = (const float*)d_in[11];
    const float* dbhh = (const float*)d_in[12];
    const float* Wc   = (const float*)d_in[13];
    const float* bc   = (const float*)d_in[14];

    float* scores = (float*)d_out;                  // [B,T,C]
    float* aw_out = scores + (size_t)BB * TT * CC;  // [B,T]

    char* ws = (char*)d_ws;
    size_t off = 0;
    auto alloc = [&](size_t bytes) -> char* {
        char* p = ws + off;
        off = (off + bytes + 255) & ~(size_t)255;
        return p;
    };

    __hip_bfloat16* Xg    = (__hip_bfloat16*)alloc((size_t)BT * G4 * 2);   // 64 MiB, [T,B,4H]
    char*           Bz    = alloc((size_t)G4 * KD * 2);                    // 16 MiB: eWhhB (enc) then Wz (dec)
    char*           Cp    = alloc((size_t)G4 * FF * 2);                    // 16 MiB: eWihB -> dWxB -> proj
    __hip_bfloat16* hts   = (__hip_bfloat16*)alloc((size_t)BT * HH * 2);   // 16 MiB: hts then hdts
    __hip_bfloat16* Wd2eT = (__hip_bfloat16*)alloc((size_t)HH * HH * 2);   // 2 MiB
    __hip_bfloat16* We2dB = (__hip_bfloat16*)alloc((size_t)HH * HH * 2);   // 2 MiB
    __hip_bfloat16* WcP   = (__hip_bfloat16*)alloc((size_t)128 * HH * 2);  // 256 KiB
    float*          encb  = (float*)alloc((size_t)G4 * 4);
    float*          badd  = (float*)alloc((size_t)G4 * 4);
    float*          bcP   = (float*)alloc((size_t)128 * 4);
    // state (zeroed each call): henc0|henc1|Z0|Z1|hdec = 1.25 MiB
    char*           state = alloc(1310720);
    __hip_bfloat16* henc0 = (__hip_bfloat16*)(state);
    __hip_bfloat16* henc1 = (__hip_bfloat16*)(state + 131072);
    __hip_bfloat16* Zb0   = (__hip_bfloat16*)(state + 262144);
    __hip_bfloat16* Zb1   = (__hip_bfloat16*)(state + 524288);
    float*          hdec  = (float*)(state + 786432);

    __hip_bfloat16* eWhhB = (__hip_bfloat16*)Bz;     // encoder phase
    __hip_bfloat16* Wz    = (__hip_bfloat16*)Bz;     // decoder phase (overwrites)
    __hip_bfloat16* eWihB = (__hip_bfloat16*)Cp;     // phase 1
    __hip_bfloat16* dWxB  = (__hip_bfloat16*)Cp;     // phase 2
    __hip_bfloat16* proj  = (__hip_bfloat16*)Cp;     // phase 3
    __hip_bfloat16* hdts  = hts;                     // decoder phase

    (void)in_sizes; (void)n_in;

    if (off > ws_size) {
        long long n = out_size;
        fill_f32<<<dim3((unsigned)((n + 255) / 256)), 256, 0, stream>>>((float*)d_out, n, 111.0f);
        return;
    }

    auto packGrid = [](long long tot) { return dim3((unsigned)((tot + 255) / 256)); };

    // ---- setup (weights gate-permuted where indexed by the 4096 dim) ----
    zero_u32<<<dim3(1280), dim3(256), 0, stream>>>((unsigned int*)state, 327680LL);
    pack_bf16<<<packGrid((long long)G4 * FF), 256, 0, stream>>>(eWih, FF, 0, eWihB, FF, G4, FF, G4, 1);
    pack_bf16<<<packGrid((long long)G4 * HH), 256, 0, stream>>>(eWhh, HH, 0, eWhhB, HH, G4, HH, G4, 1);
    packT_bf16<<<packGrid((long long)HH * HH), 256, 0, stream>>>(Wd2e, HH, HH, Wd2eT);
    pack_bf16<<<packGrid((long long)HH * HH), 256, 0, stream>>>(We2d, HH, 0, We2dB, HH, HH, HH, HH, 0);
    pack_bf16<<<packGrid((long long)128 * HH), 256, 0, stream>>>(Wc, HH, 0, WcP, HH, 128, HH, CC, 0);
    add_bias2_perm<<<16, 256, 0, stream>>>(ebih, ebhh, encb, G4);
    pad_bias<<<1, 128, 0, stream>>>(bc, bcP, CC, 128);
    bcomb_kernel<<<G4, 64, 0, stream>>>(dWih, bd2e, dbih, dbhh, badd);

    // enc Xg = bf16(x @ enc_Wih^T + bias)  -> [T,B,4096] (rowmap=2)
    gemm_tile<FF, true><<<dim3(BT / 128, G4 / 128), 256, 0, stream>>>(
        x, FF, eWihB, encb, Xg, 1, G4, G4, 2);

    // ---- persistent encoder (cooperative) ----
    {
        const __hip_bfloat16* a0 = eWhhB; const __hip_bfloat16* a1 = Xg;
        __hip_bfloat16* a2 = henc0; __hip_bfloat16* a3 = henc1; __hip_bfloat16* a4 = hts;
        void* args[5] = { &a0, &a1, &a2, &a3, &a4 };
        hipLaunchCooperativeKernel((const void*)enc_persist, dim3(256), dim3(256), args, 0, stream);
    }

    // dec Xg = bf16(x @ dec_Wih[:, :F]^T + badd)  (Cp: eWihB -> dWxB)
    pack_bf16<<<packGrid((long long)G4 * FF), 256, 0, stream>>>(dWih, FF + HH, 0, dWxB, FF, G4, FF, G4, 1);
    gemm_tile<FF, true><<<dim3(BT / 128, G4 / 128), 256, 0, stream>>>(
        x, FF, dWxB, badd, Xg, 1, G4, G4, 2);

    // Wz[:, 0:1024] = perm_rows(dec_Wih[:, F:] @ Wd2e)
    gemm_tile<HH, true><<<dim3(G4 / 128, HH / 128), 256, 0, stream>>>(
        dWih + FF, FF + HH, Wd2eT, nullptr, Wz, 1, KD, HH, 1);
    // Wz[:, 1024:2048] = perm_rows(dec_Whh)
    pack_bf16<<<packGrid((long long)G4 * HH), 256, 0, stream>>>(dWhh, HH, 0, Wz + HH, KD, G4, HH, G4, 1);

    // proj = h_ts @ We2d^T + be2d  (bf16 out; Cp: dWxB -> proj)
    gemm_tile<HH, false><<<dim3(BT / 128, HH / 128), 256, 0, stream>>>(
        hts, HH, We2dB, be2d, proj, 1, HH, HH, 0);

    // ---- persistent decoder (cooperative) ----
    {
        const __hip_bfloat16* a0 = Wz; const __hip_bfloat16* a1 = Xg;
        const __hip_bfloat16* a2 = proj;
        __hip_bfloat16* a3 = Zb0; __hip_bfloat16* a4 = Zb1;
        float* a5 = hdec; __hip_bfloat16* a6 = hdts; float* a7 = aw_out;
        void* args[8] = { &a0, &a1, &a2, &a3, &a4, &a5, &a6, &a7 };
        hipLaunchCooperativeKernel((const void*)dec_persist, dim3(256), dim3(256), args, 0, stream);
    }

    // scores = h_dec_ts @ Wc^T + bc
    gemm_tile<HH, false><<<dim3(BT / 128, 1), 256, 0, stream>>>(
        hdts, HH, WcP, bcP, scores, 0, CC, CC, 0);
}